// Round 8
// baseline (385.382 us; speedup 1.0000x reference)
//
#include <hip/hip_runtime.h>
#include <stdint.h>

// ---------------------------------------------------------------------------
// Net_60129542953 R8:
//  - agg_ln + LayerNorm + GEMM3 fused into one kernel: gather+LN staged
//    straight into the MFMA A-tile (LDS), w3t streamed via global_load_lds,
//    z never materialized (saves 51 MB round trip + a launch).
//  - dinv folded into scan_part; scan_bsums folded into scan_final;
//    x-convert + weight-converts merged into one kernel. 15 -> 12 launches.
// ---------------------------------------------------------------------------

#define C_IN  128
#define C_HID 256
#define C_OUT 128
#define SCAN_B 256

typedef __attribute__((ext_vector_type(8))) short bf16x8;
typedef __attribute__((ext_vector_type(4))) float f32x4;

__device__ __forceinline__ short f2bf(float f) {
  union { float f; uint32_t u; } v; v.f = f;
  uint32_t r = v.u + 0x7FFFu + ((v.u >> 16) & 1u);  // RNE
  return (short)(r >> 16);
}
__device__ __forceinline__ uint32_t pack_bf2(float a, float b) {
  return (uint32_t)(uint16_t)f2bf(a) | ((uint32_t)(uint16_t)f2bf(b) << 16);
}
__device__ __forceinline__ float bflo(uint32_t p) {
  union { uint32_t u; float f; } v; v.u = p << 16; return v.f;
}
__device__ __forceinline__ float bfhi(uint32_t p) {
  union { uint32_t u; float f; } v; v.u = p & 0xffff0000u; return v.f;
}
__device__ __forceinline__ float bfs(short s) {
  union { uint32_t u; float f; } v; v.u = ((uint32_t)(uint16_t)s) << 16; return v.f;
}

__device__ __forceinline__ void acc8(float* a, uint4 p, float w) {
  a[0] += bflo(p.x) * w; a[1] += bfhi(p.x) * w;
  a[2] += bflo(p.y) * w; a[3] += bfhi(p.y) * w;
  a[4] += bflo(p.z) * w; a[5] += bfhi(p.z) * w;
  a[6] += bflo(p.w) * w; a[7] += bfhi(p.w) * w;
}

__device__ __forceinline__ void async_cp16(const void* g, void* l) {
  __builtin_amdgcn_global_load_lds((const __attribute__((address_space(1))) void*)g,
                                   (__attribute__((address_space(3))) void*)l, 16, 0, 0);
}

// ---------------- CSR build ----------------

__global__ __launch_bounds__(256) void hist_kernel(const int* __restrict__ dst,
                                                   int* __restrict__ counts,
                                                   int* __restrict__ ofs, int E) {
  int e = blockIdx.x * 256 + threadIdx.x;
  if (e < E) ofs[e] = atomicAdd(&counts[dst[e]], 1);
}

// phase A: block b sums its chunk of counts; also computes dinv
__global__ __launch_bounds__(256) void scan_part(const int* __restrict__ counts,
                                                 int* __restrict__ blockSums,
                                                 float* __restrict__ dinv,
                                                 int n, int per) {
  __shared__ int ws[4];
  int b = blockIdx.x;
  int start = b * per, end = min(n, start + per);
  int s = 0;
  for (int i = start + threadIdx.x; i < end; i += 256) {
    int c = counts[i];
    s += c;
    dinv[i] = rsqrtf((float)c + 1.0f);  // deg = indeg + 1 (self loop)
  }
#pragma unroll
  for (int d = 1; d < 64; d <<= 1) s += __shfl_xor(s, d);
  if ((threadIdx.x & 63) == 0) ws[threadIdx.x >> 6] = s;
  __syncthreads();
  if (threadIdx.x == 0) blockSums[b] = ws[0] + ws[1] + ws[2] + ws[3];
}

// phase B: block b derives its base offset from blockSums, scans its chunk
__global__ __launch_bounds__(256) void scan_final(const int* __restrict__ counts,
                                                  const int* __restrict__ blockSums,
                                                  int* __restrict__ row_ptr,
                                                  int n, int per) {
  __shared__ int wsum[4];
  __shared__ int sbase;
  int tid = threadIdx.x, lane = tid & 63, wid = tid >> 6;
  int b = blockIdx.x;
  // base = sum blockSums[0..b)
  {
    int v = (tid < b) ? blockSums[tid] : 0;
#pragma unroll
    for (int d = 1; d < 64; d <<= 1) v += __shfl_xor(v, d);
    if (lane == 0) wsum[wid] = v;
    __syncthreads();
    if (tid == 0) sbase = wsum[0] + wsum[1] + wsum[2] + wsum[3];
    __syncthreads();
  }
  int start = b * per, end = min(n + 1, start + per);
  for (int chunk = start; chunk < end; chunk += 256) {
    int idx = chunk + tid;
    int v = (idx < n) ? counts[idx] : 0;
    int x = v;
#pragma unroll
    for (int d = 1; d < 64; d <<= 1) {
      int y = __shfl_up(x, d, 64);
      if (lane >= d) x += y;
    }
    if (lane == 63) wsum[wid] = x;
    __syncthreads();
    if (tid == 0) {
      int run = sbase;
#pragma unroll
      for (int w = 0; w < 4; ++w) { int t = wsum[w]; wsum[w] = run; run += t; }
      sbase = run;
    }
    __syncthreads();
    if (idx < end) row_ptr[idx] = wsum[wid] + x - v;
    __syncthreads();
  }
}

// edges[row_ptr[d]+ofs[e]] = {src, dinv[src]*dinv[dst]}  (no atomics)
__global__ __launch_bounds__(256) void place_kernel(const int* __restrict__ src,
                                                    const int* __restrict__ dst,
                                                    const int* __restrict__ row_ptr,
                                                    const int* __restrict__ ofs,
                                                    const float* __restrict__ dinv,
                                                    int2* __restrict__ edges, int E) {
  int e = blockIdx.x * 256 + threadIdx.x;
  if (e < E) {
    int d = dst[e], s = src[e];
    int pos = row_ptr[d] + ofs[e];
    int2 ed; ed.x = s; ed.y = __float_as_int(dinv[s] * dinv[d]);
    edges[pos] = ed;
  }
}

// ---------------- Conversions (x + all weights, one launch) ----------------

__global__ __launch_bounds__(256) void cvt_all(const float* __restrict__ x,
                                               short* __restrict__ x_bf, int n4,
                                               const float* __restrict__ W1,
                                               short* __restrict__ w1t,
                                               const float* __restrict__ W2,
                                               short* __restrict__ w2t,
                                               const float* __restrict__ W3,
                                               short* __restrict__ w3t) {
  int i = blockIdx.x * 256 + threadIdx.x;
  if (i < n4) {
    float4 v = ((const float4*)x)[i];
    short4 o;
    o.x = f2bf(v.x); o.y = f2bf(v.y); o.z = f2bf(v.z); o.w = f2bf(v.w);
    ((short4*)x_bf)[i] = o;
    return;
  }
  int j = i - n4;
  if (j < 32768) {                       // W1 [k=128][n=256]
    int k = j >> 8, n = j & 255;
    w1t[n * 128 + k] = f2bf(W1[j]);
  } else if (j < 65536) {                // W2 [k=256][n=128]
    int jj = j - 32768; int k = jj >> 7, n = jj & 127;
    w2t[n * 256 + k] = f2bf(W2[jj]);
  } else if (j < 81920) {                // W3 [k=128][n=128]
    int jj = j - 65536; int k = jj >> 7, n = jj & 127;
    w3t[n * 128 + k] = f2bf(W3[jj]);
  }
}

// ---------------- bf16 MFMA GEMM: C[M,N] = A[M,K] @ BT[N,K]^T (+bias) -------
// 128x128 tile, BK=128, XOR-swizzled LDS, LDS-staged coalesced bf16 C stores.
// MODE 2: + non-atomic BN partials; MODE 3: BN-apply+ReLU fused into A staging.

template <int MODE>
__global__ __launch_bounds__(256, 2) void bgemm_big(const short* __restrict__ A,
                                                    const short* __restrict__ BT,
                                                    const float* __restrict__ bias,
                                                    short* __restrict__ Cout,
                                                    float* __restrict__ pS,
                                                    float* __restrict__ pSS,
                                                    const float* __restrict__ bnp,
                                                    int M, int N, int K) {
  __shared__ short smem[2 * 128 * 128];  // 64 KB
  short* As = smem;
  short* Bs = smem + 128 * 128;
  const int tid = threadIdx.x;
  const int w = tid >> 6, lane = tid & 63;
  const int wM = w >> 1, wN = w & 1;
  const int rowBase = blockIdx.y * 128;
  const int colBase = blockIdx.x * 128;
  const int l15 = lane & 15, q = lane >> 4;

  f32x4 acc[4][4];
#pragma unroll
  for (int i = 0; i < 4; ++i)
#pragma unroll
    for (int j = 0; j < 4; ++j) acc[i][j] = (f32x4){0.f, 0.f, 0.f, 0.f};

  for (int k0 = 0; k0 < K; k0 += 128) {
    if (MODE == 3) {
#pragma unroll
      for (int it = 0; it < 8; ++it) {
        int p = it * 256 + tid;
        int row = p >> 4, kcp = p & 15;
        int kc = kcp ^ (row & 15);
        int gm = rowBase + row; if (gm >= M) gm = M - 1;
        int c = k0 + kc * 8;
        bf16x8 av = *(const bf16x8*)&A[(size_t)gm * K + c];
        float4 s0 = *(const float4*)&bnp[c];
        float4 s1 = *(const float4*)&bnp[c + 4];
        float4 h0 = *(const float4*)&bnp[K + c];
        float4 h1 = *(const float4*)&bnp[K + c + 4];
        short res[8];
        res[0] = f2bf(fmaxf(bfs(av[0]) * s0.x + h0.x, 0.f));
        res[1] = f2bf(fmaxf(bfs(av[1]) * s0.y + h0.y, 0.f));
        res[2] = f2bf(fmaxf(bfs(av[2]) * s0.z + h0.z, 0.f));
        res[3] = f2bf(fmaxf(bfs(av[3]) * s0.w + h0.w, 0.f));
        res[4] = f2bf(fmaxf(bfs(av[4]) * s1.x + h1.x, 0.f));
        res[5] = f2bf(fmaxf(bfs(av[5]) * s1.y + h1.y, 0.f));
        res[6] = f2bf(fmaxf(bfs(av[6]) * s1.z + h1.z, 0.f));
        res[7] = f2bf(fmaxf(bfs(av[7]) * s1.w + h1.w, 0.f));
        bf16x8 rv;
#pragma unroll
        for (int j = 0; j < 8; ++j) rv[j] = res[j];
        *(bf16x8*)&As[p * 8] = rv;
      }
    } else {
#pragma unroll
      for (int it = 0; it < 8; ++it) {
        int p = it * 256 + tid;
        int row = p >> 4, kcp = p & 15;
        int kc = kcp ^ (row & 15);
        int gm = rowBase + row; if (gm >= M) gm = M - 1;  // clamp; stores guarded
        async_cp16(A + (size_t)gm * K + k0 + kc * 8, &As[(it * 256 + w * 64) * 8]);
      }
    }
#pragma unroll
    for (int it = 0; it < 8; ++it) {
      int p = it * 256 + tid;
      int row = p >> 4, kcp = p & 15;
      int kc = kcp ^ (row & 15);
      async_cp16(BT + (size_t)(colBase + row) * K + k0 + kc * 8,
                 &Bs[(it * 256 + w * 64) * 8]);
    }
    __syncthreads();

#pragma unroll
    for (int ks = 0; ks < 4; ++ks) {
      bf16x8 af[4], bfr[4];
#pragma unroll
      for (int tm = 0; tm < 4; ++tm) {
        int row = wM * 64 + tm * 16 + l15;
        int kcp = (ks * 4 + q) ^ l15;
        af[tm] = *(const bf16x8*)&As[(row * 16 + kcp) * 8];
      }
#pragma unroll
      for (int tn = 0; tn < 4; ++tn) {
        int row = wN * 64 + tn * 16 + l15;
        int kcp = (ks * 4 + q) ^ l15;
        bfr[tn] = *(const bf16x8*)&Bs[(row * 16 + kcp) * 8];
      }
#pragma unroll
      for (int tm = 0; tm < 4; ++tm)
#pragma unroll
        for (int tn = 0; tn < 4; ++tn)
          acc[tm][tn] = __builtin_amdgcn_mfma_f32_16x16x32_bf16(af[tm], bfr[tn],
                                                                acc[tm][tn], 0, 0, 0);
    }
    __syncthreads();
  }

  if (MODE == 2) {
#pragma unroll
    for (int tn = 0; tn < 4; ++tn) {
      int col = colBase + wN * 64 + tn * 16 + l15;
      float bv = bias ? bias[col] : 0.0f;
      float s = 0.f, ss = 0.f;
#pragma unroll
      for (int tm = 0; tm < 4; ++tm) {
        int r0 = rowBase + wM * 64 + tm * 16 + q * 4;
#pragma unroll
        for (int r = 0; r < 4; ++r) {
          if (r0 + r < M) { float v = acc[tm][tn][r] + bv; s += v; ss += v * v; }
        }
      }
      s += __shfl_xor(s, 16); s += __shfl_xor(s, 32);
      ss += __shfl_xor(ss, 16); ss += __shfl_xor(ss, 32);
      if (q == 0) {
        int prow = blockIdx.y * 2 + wM;
        pS[(size_t)prow * C_HID + col] = s;
        pSS[(size_t)prow * C_HID + col] = ss;
      }
    }
  }

  {
    short* S = As;
#pragma unroll
    for (int tn = 0; tn < 4; ++tn) {
      int col = wN * 64 + tn * 16 + l15;
      float bv = bias ? bias[colBase + col] : 0.0f;
#pragma unroll
      for (int tm = 0; tm < 4; ++tm) {
        int r0 = wM * 64 + tm * 16 + q * 4;
#pragma unroll
        for (int r = 0; r < 4; ++r) S[(r0 + r) * 128 + col] = f2bf(acc[tm][tn][r] + bv);
      }
    }
    __syncthreads();
#pragma unroll
    for (int it = 0; it < 8; ++it) {
      int p = it * 256 + tid;
      int row = p >> 4, c = p & 15;
      int gm = rowBase + row;
      if (gm < M)
        *(uint4*)&Cout[(size_t)gm * N + colBase + c * 8] = ((const uint4*)S)[p];
    }
  }
}

// ---------------- Fused agg + LN + ReLU + GEMM3 (N = K = 128) ---------------
// Each 16-lane group gathers+LNs 8 rows straight into the swizzled A-tile;
// B (w3t) streams via global_load_lds concurrently; then the MFMA loop and a
// coalesced bf16 epilogue. z is never materialized.

__global__ __launch_bounds__(256, 2) void fused_ln_gemm3(
    const uint4* __restrict__ hb4, const float* __restrict__ dinv,
    const int* __restrict__ row_ptr, const int2* __restrict__ edges,
    const float* __restrict__ b2, const float* __restrict__ gamma,
    const float* __restrict__ beta, const short* __restrict__ BT,
    const float* __restrict__ bias, short* __restrict__ Cout, int M) {
  __shared__ short As[128 * 128];  // 32 KB
  __shared__ short Bs[128 * 128];  // 32 KB
  const int tid = threadIdx.x;
  const int w = tid >> 6, lane = tid & 63;
  const int wM = w >> 1, wN = w & 1;
  const int rowBase = blockIdx.x * 128;
  const int l15 = lane & 15, q = lane >> 4;
  const int g16 = tid >> 4, sl = tid & 15;

  // B staging (async, overlaps the gather below)
#pragma unroll
  for (int it = 0; it < 8; ++it) {
    int p = it * 256 + tid;
    int row = p >> 4, kcp = p & 15;
    int kc = kcp ^ (row & 15);
    async_cp16(BT + (size_t)row * 128 + kc * 8, &Bs[(it * 256 + w * 64) * 8]);
  }

  // A staging: group g16 handles rows g16*8 .. g16*8+7 (gather + LN + ReLU)
  int c = sl * 8;
  float4 bv0 = *(const float4*)&b2[c];
  float4 bv1 = *(const float4*)&b2[c + 4];
  float4 g0 = *(const float4*)&gamma[c];
  float4 g1 = *(const float4*)&gamma[c + 4];
  float4 t0 = *(const float4*)&beta[c];
  float4 t1 = *(const float4*)&beta[c + 4];
#pragma unroll
  for (int r = 0; r < 8; ++r) {
    int rowLocal = g16 * 8 + r;
    int gm = rowBase + rowLocal; if (gm >= M) gm = M - 1;
    int e0 = row_ptr[gm], e1 = row_ptr[gm + 1];
    float a[8] = {0.f, 0.f, 0.f, 0.f, 0.f, 0.f, 0.f, 0.f};
    int e = e0;
    for (; e + 4 <= e1; e += 4) {
      int2 ed0 = edges[e], ed1 = edges[e + 1], ed2 = edges[e + 2], ed3 = edges[e + 3];
      uint4 p0 = hb4[(size_t)ed0.x * 16 + sl];
      uint4 p1 = hb4[(size_t)ed1.x * 16 + sl];
      uint4 p2 = hb4[(size_t)ed2.x * 16 + sl];
      uint4 p3 = hb4[(size_t)ed3.x * 16 + sl];
      acc8(a, p0, __int_as_float(ed0.y));
      acc8(a, p1, __int_as_float(ed1.y));
      acc8(a, p2, __int_as_float(ed2.y));
      acc8(a, p3, __int_as_float(ed3.y));
    }
    for (; e < e1; ++e) {
      int2 ed = edges[e];
      uint4 p = hb4[(size_t)ed.x * 16 + sl];
      acc8(a, p, __int_as_float(ed.y));
    }
    float dn = dinv[gm];
    uint4 ps = hb4[(size_t)gm * 16 + sl];
    acc8(a, ps, dn * dn);
    a[0] += bv0.x; a[1] += bv0.y; a[2] += bv0.z; a[3] += bv0.w;
    a[4] += bv1.x; a[5] += bv1.y; a[6] += bv1.z; a[7] += bv1.w;

    float s = 0.f, ss = 0.f;
#pragma unroll
    for (int j = 0; j < 8; ++j) { s += a[j]; ss += a[j] * a[j]; }
#pragma unroll
    for (int d = 1; d < 16; d <<= 1) {  // within the 16-lane group
      s += __shfl_xor(s, d);
      ss += __shfl_xor(ss, d);
    }
    float mu = s * (1.0f / C_OUT);
    float var = ss * (1.0f / C_OUT) - mu * mu;
    float rs = rsqrtf(var + 1e-5f);
    bf16x8 rv;
    rv[0] = f2bf(fmaxf((a[0] - mu) * rs * g0.x + t0.x, 0.f));
    rv[1] = f2bf(fmaxf((a[1] - mu) * rs * g0.y + t0.y, 0.f));
    rv[2] = f2bf(fmaxf((a[2] - mu) * rs * g0.z + t0.z, 0.f));
    rv[3] = f2bf(fmaxf((a[3] - mu) * rs * g0.w + t0.w, 0.f));
    rv[4] = f2bf(fmaxf((a[4] - mu) * rs * g1.x + t1.x, 0.f));
    rv[5] = f2bf(fmaxf((a[5] - mu) * rs * g1.y + t1.y, 0.f));
    rv[6] = f2bf(fmaxf((a[6] - mu) * rs * g1.z + t1.z, 0.f));
    rv[7] = f2bf(fmaxf((a[7] - mu) * rs * g1.w + t1.w, 0.f));
    int kcp = sl ^ (rowLocal & 15);  // swizzled chunk slot
    *(bf16x8*)&As[(rowLocal * 16 + kcp) * 8] = rv;
  }
  __syncthreads();  // drains B async + A ds_writes

  f32x4 acc[4][4];
#pragma unroll
  for (int i = 0; i < 4; ++i)
#pragma unroll
    for (int j = 0; j < 4; ++j) acc[i][j] = (f32x4){0.f, 0.f, 0.f, 0.f};

#pragma unroll
  for (int ks = 0; ks < 4; ++ks) {
    bf16x8 af[4], bfr[4];
#pragma unroll
    for (int tm = 0; tm < 4; ++tm) {
      int row = wM * 64 + tm * 16 + l15;
      int kcp = (ks * 4 + q) ^ l15;
      af[tm] = *(const bf16x8*)&As[(row * 16 + kcp) * 8];
    }
#pragma unroll
    for (int tn = 0; tn < 4; ++tn) {
      int row = wN * 64 + tn * 16 + l15;
      int kcp = (ks * 4 + q) ^ l15;
      bfr[tn] = *(const bf16x8*)&Bs[(row * 16 + kcp) * 8];
    }
#pragma unroll
    for (int tm = 0; tm < 4; ++tm)
#pragma unroll
      for (int tn = 0; tn < 4; ++tn)
        acc[tm][tn] = __builtin_amdgcn_mfma_f32_16x16x32_bf16(af[tm], bfr[tn],
                                                              acc[tm][tn], 0, 0, 0);
  }
  __syncthreads();

  // epilogue: stage bf16 tile, coalesced stores
  {
    short* S = As;
#pragma unroll
    for (int tn = 0; tn < 4; ++tn) {
      int col = wN * 64 + tn * 16 + l15;
      float bv = bias[col];
#pragma unroll
      for (int tm = 0; tm < 4; ++tm) {
        int r0 = wM * 64 + tm * 16 + q * 4;
#pragma unroll
        for (int r = 0; r < 4; ++r) S[(r0 + r) * 128 + col] = f2bf(acc[tm][tn][r] + bv);
      }
    }
    __syncthreads();
#pragma unroll
    for (int it = 0; it < 8; ++it) {
      int p = it * 256 + tid;
      int row = p >> 4, cc = p & 15;
      int gm = rowBase + row;
      if (gm < M)
        *(uint4*)&Cout[(size_t)gm * 128 + cc * 8] = ((const uint4*)S)[p];
    }
  }
}

// ---------------- BN stats tree reduce ----------------

__global__ __launch_bounds__(256) void bn_red1_kernel(const float* __restrict__ pS,
                                                      const float* __restrict__ pSS,
                                                      float* __restrict__ oS,
                                                      float* __restrict__ oSS, int R) {
  int c = threadIdx.x;
  int per = (R + gridDim.x - 1) / gridDim.x;
  int r0 = blockIdx.x * per, r1 = min(R, r0 + per);
  float s = 0.f, ss = 0.f;
  for (int r = r0; r < r1; ++r) {
    s += pS[(size_t)r * C_HID + c];
    ss += pSS[(size_t)r * C_HID + c];
  }
  oS[(size_t)blockIdx.x * C_HID + c] = s;
  oSS[(size_t)blockIdx.x * C_HID + c] = ss;
}

__global__ __launch_bounds__(256) void bn_red2_kernel(const float* __restrict__ oS,
                                                      const float* __restrict__ oSS,
                                                      const float* __restrict__ gamma,
                                                      const float* __restrict__ beta,
                                                      float* __restrict__ bnp,
                                                      int G, float invN) {
  int c = threadIdx.x;
  float s = 0.f, ss = 0.f;
  for (int g = 0; g < G; ++g) {
    s += oS[(size_t)g * C_HID + c];
    ss += oSS[(size_t)g * C_HID + c];
  }
  float mu = s * invN;
  float var = ss * invN - mu * mu;
  float sc = gamma[c] * rsqrtf(var + 1e-5f);
  bnp[c] = sc;
  bnp[C_HID + c] = beta[c] - mu * sc;
}

// ---------------- agg_x: 16-lane group per node, unroll x4 ----------------

__global__ __launch_bounds__(256) void agg_x_kernel(const uint4* __restrict__ xb4,
                                                    const float* __restrict__ dinv,
                                                    const int* __restrict__ row_ptr,
                                                    const int2* __restrict__ edges,
                                                    uint4* __restrict__ out4, int N) {
  int g = (blockIdx.x * 256 + threadIdx.x) >> 4;
  int sl = threadIdx.x & 15;
  if (g >= N) return;
  int e0 = row_ptr[g], e1 = row_ptr[g + 1];
  float a[8] = {0.f, 0.f, 0.f, 0.f, 0.f, 0.f, 0.f, 0.f};
  int e = e0;
  for (; e + 4 <= e1; e += 4) {
    int2 ed0 = edges[e], ed1 = edges[e + 1], ed2 = edges[e + 2], ed3 = edges[e + 3];
    uint4 p0 = xb4[(size_t)ed0.x * 16 + sl];
    uint4 p1 = xb4[(size_t)ed1.x * 16 + sl];
    uint4 p2 = xb4[(size_t)ed2.x * 16 + sl];
    uint4 p3 = xb4[(size_t)ed3.x * 16 + sl];
    acc8(a, p0, __int_as_float(ed0.y));
    acc8(a, p1, __int_as_float(ed1.y));
    acc8(a, p2, __int_as_float(ed2.y));
    acc8(a, p3, __int_as_float(ed3.y));
  }
  for (; e < e1; ++e) {
    int2 ed = edges[e];
    uint4 p = xb4[(size_t)ed.x * 16 + sl];
    acc8(a, p, __int_as_float(ed.y));
  }
  float dn = dinv[g];
  uint4 ps = xb4[(size_t)g * 16 + sl];
  acc8(a, ps, dn * dn);
  uint4 o;
  o.x = pack_bf2(a[0], a[1]); o.y = pack_bf2(a[2], a[3]);
  o.z = pack_bf2(a[4], a[5]); o.w = pack_bf2(a[6], a[7]);
  out4[(size_t)g * 16 + sl] = o;
}

// ---------------- Decode: 16-lane group per pair, bf16 z rows ---------------

__global__ __launch_bounds__(256) void decode_kernel(const uint4* __restrict__ zb4,
                                                     const int* __restrict__ eli,
                                                     const float* __restrict__ cutoff,
                                                     float* __restrict__ out, int EL) {
  int g = (blockIdx.x * 256 + threadIdx.x) >> 4;
  int sl = threadIdx.x & 15;
  if (g >= EL) return;
  int a = eli[g];
  int b = eli[EL + g];
  uint4 va = zb4[(size_t)a * 16 + sl];
  uint4 vb = zb4[(size_t)b * 16 + sl];
  float s = bflo(va.x) * bflo(vb.x) + bfhi(va.x) * bfhi(vb.x)
          + bflo(va.y) * bflo(vb.y) + bfhi(va.y) * bfhi(vb.y)
          + bflo(va.z) * bflo(vb.z) + bfhi(va.z) * bfhi(vb.z)
          + bflo(va.w) * bflo(vb.w) + bfhi(va.w) * bfhi(vb.w);
#pragma unroll
  for (int d = 1; d < 16; d <<= 1) s += __shfl_xor(s, d);
  if (sl == 0) {
    out[g] = s;
    out[EL + g] = (s < cutoff[0]) ? 0.0f : 1.0f;
  }
}

// ---------------- Launch ----------------

extern "C" void kernel_launch(void* const* d_in, const int* in_sizes, int n_in,
                              void* d_out, int out_size, void* d_ws, size_t ws_size,
                              hipStream_t stream) {
  const float* x        = (const float*)d_in[0];
  const int*   eidx     = (const int*)d_in[1];
  const int*   eli      = (const int*)d_in[2];
  const float* cutoff   = (const float*)d_in[3];
  const float* W1       = (const float*)d_in[4];
  const float* b1       = (const float*)d_in[5];
  const float* bn_gamma = (const float*)d_in[6];
  const float* bn_beta  = (const float*)d_in[7];
  const float* W2       = (const float*)d_in[8];
  const float* b2       = (const float*)d_in[9];
  const float* ln_gamma = (const float*)d_in[10];
  const float* ln_beta  = (const float*)d_in[11];
  const float* lin_W    = (const float*)d_in[12];
  const float* lin_b    = (const float*)d_in[13];
  float* out = (float*)d_out;

  const int N  = in_sizes[0] / C_IN;   // 100000
  const int E  = in_sizes[1] / 2;      // 800000
  const int EL = in_sizes[2] / 2;      // 200000

  const int* src = eidx;
  const int* dst = eidx + E;

  const int MB = (N + 127) / 128;
  const int R  = 2 * MB;

  // workspace layout
  char* p = (char*)d_ws;
  short* regionA = (short*)p;  p += (size_t)N * 256 * 2;  // x_bf+xa_bf, later zf_bf
  short* regionB = (short*)p;  p += (size_t)N * 256 * 2;  // h1_bf
  short* h2_bf   = (short*)p;  p += (size_t)N * 128 * 2;
  float* dinv    = (float*)p;  p += (size_t)N * 4;
  int* counts    = (int*)p;    p += (size_t)N * 4;
  int* row_ptr   = (int*)p;    p += (size_t)(N + 4) * 4;
  int* ofs       = (int*)p;    p += (size_t)E * 4;
  int2* edges    = (int2*)p;   p += (size_t)E * 8;
  float* pS      = (float*)p;  p += (size_t)R * C_HID * 4;
  float* pSS     = (float*)p;  p += (size_t)R * C_HID * 4;
  float* oS      = (float*)p;  p += 32 * C_HID * 4;
  float* oSS     = (float*)p;  p += 32 * C_HID * 4;
  float* bnp     = (float*)p;  p += 2 * C_HID * 4;
  int* blockSums = (int*)p;    p += SCAN_B * 4;
  short* w1t     = (short*)p;  p += (size_t)C_HID * C_IN * 2;
  short* w2t     = (short*)p;  p += (size_t)C_OUT * C_HID * 2;
  short* w3t     = (short*)p;  p += (size_t)C_OUT * C_OUT * 2;

  short* x_bf   = regionA;                    // [N][128]
  short* xa_bf  = regionA + (size_t)N * 128;  // [N][128]
  short* h1_bf  = regionB;                    // [N][256]
  short* zf_bf  = regionA;                    // [N][128] (x/xa dead after GEMM1)

  hipMemsetAsync(counts, 0, (size_t)N * 4, stream);

  int eb = (E + 255) / 256;

  hist_kernel<<<eb, 256, 0, stream>>>(dst, counts, ofs, E);

  int per = (N + 1 + SCAN_B - 1) / SCAN_B;
  scan_part<<<SCAN_B, 256, 0, stream>>>(counts, blockSums, dinv, N, per);
  scan_final<<<SCAN_B, 256, 0, stream>>>(counts, blockSums, row_ptr, N, per);

  place_kernel<<<eb, 256, 0, stream>>>(src, dst, row_ptr, ofs, dinv, edges, E);

  int xn4 = N * C_IN / 4;
  cvt_all<<<(xn4 + 81920 + 255) / 256, 256, 0, stream>>>(x, x_bf, xn4, W1, w1t,
                                                         W2, w2t, lin_W, w3t);

  int gb = ((size_t)N * 16 + 255) / 256;  // 16-lane group per node
  agg_x_kernel<<<gb, 256, 0, stream>>>((const uint4*)x_bf, dinv, row_ptr, edges,
                                       (uint4*)xa_bf, N);

  // GEMM1: h1 = agg(x) @ W1 + b1  [N x 256] bf16 + BN partials
  dim3 g1(C_HID / 128, MB);
  bgemm_big<2><<<g1, 256, 0, stream>>>(xa_bf, w1t, b1, h1_bf, pS, pSS, nullptr,
                                       N, C_HID, C_IN);

  bn_red1_kernel<<<32, 256, 0, stream>>>(pS, pSS, oS, oSS, R);
  bn_red2_kernel<<<1, 256, 0, stream>>>(oS, oSS, bn_gamma, bn_beta, bnp, 32,
                                        1.0f / (float)N);

  // GEMM2: h2raw = relu(bn(h1)) @ W2  [N x 128] bf16; BN fused into A staging
  dim3 g2(C_OUT / 128, MB);
  bgemm_big<3><<<g2, 256, 0, stream>>>(h1_bf, w2t, nullptr, h2_bf, nullptr, nullptr,
                                       bnp, N, C_OUT, C_HID);

  // fused: zf = relu(LN(agg(h2)+b2)) @ lin_W + lin_b  [N x 128] bf16
  fused_ln_gemm3<<<MB, 256, 0, stream>>>((const uint4*)h2_bf, dinv, row_ptr, edges,
                                         b2, ln_gamma, ln_beta, w3t, lin_b,
                                         zf_bf, N);

  int db = ((size_t)EL * 16 + 255) / 256;  // 16-lane group per pair
  decode_kernel<<<db, 256, 0, stream>>>((const uint4*)zf_bf, eli, cutoff, out, EL);
}

// Round 9
// 358.725 us; speedup vs baseline: 1.0743x; 1.0743x over previous
//
#include <hip/hip_runtime.h>
#include <stdint.h>

// ---------------------------------------------------------------------------
// Net_60129542953 R9:
//  - REVERT R8's agg+LN+GEMM3 fusion (81.6us fused vs ~55us separate: 64KB
//    LDS capped occupancy at 2 blocks/CU, strangling the latency-bound
//    gather's memory-level parallelism). Back to separate agg_ln + GEMM3.
//  - KEEP R8's launch consolidation: dinv folded into scan_part, 2-phase
//    scan, single cvt_all kernel.
// ---------------------------------------------------------------------------

#define C_IN  128
#define C_HID 256
#define C_OUT 128
#define SCAN_B 256

typedef __attribute__((ext_vector_type(8))) short bf16x8;
typedef __attribute__((ext_vector_type(4))) float f32x4;

__device__ __forceinline__ short f2bf(float f) {
  union { float f; uint32_t u; } v; v.f = f;
  uint32_t r = v.u + 0x7FFFu + ((v.u >> 16) & 1u);  // RNE
  return (short)(r >> 16);
}
__device__ __forceinline__ uint32_t pack_bf2(float a, float b) {
  return (uint32_t)(uint16_t)f2bf(a) | ((uint32_t)(uint16_t)f2bf(b) << 16);
}
__device__ __forceinline__ float bflo(uint32_t p) {
  union { uint32_t u; float f; } v; v.u = p << 16; return v.f;
}
__device__ __forceinline__ float bfhi(uint32_t p) {
  union { uint32_t u; float f; } v; v.u = p & 0xffff0000u; return v.f;
}
__device__ __forceinline__ float bfs(short s) {
  union { uint32_t u; float f; } v; v.u = ((uint32_t)(uint16_t)s) << 16; return v.f;
}

__device__ __forceinline__ void acc8(float* a, uint4 p, float w) {
  a[0] += bflo(p.x) * w; a[1] += bfhi(p.x) * w;
  a[2] += bflo(p.y) * w; a[3] += bfhi(p.y) * w;
  a[4] += bflo(p.z) * w; a[5] += bfhi(p.z) * w;
  a[6] += bflo(p.w) * w; a[7] += bfhi(p.w) * w;
}

__device__ __forceinline__ void async_cp16(const void* g, void* l) {
  __builtin_amdgcn_global_load_lds((const __attribute__((address_space(1))) void*)g,
                                   (__attribute__((address_space(3))) void*)l, 16, 0, 0);
}

// ---------------- CSR build ----------------

__global__ __launch_bounds__(256) void hist_kernel(const int* __restrict__ dst,
                                                   int* __restrict__ counts,
                                                   int* __restrict__ ofs, int E) {
  int e = blockIdx.x * 256 + threadIdx.x;
  if (e < E) ofs[e] = atomicAdd(&counts[dst[e]], 1);
}

// phase A: block b sums its chunk of counts; also computes dinv
__global__ __launch_bounds__(256) void scan_part(const int* __restrict__ counts,
                                                 int* __restrict__ blockSums,
                                                 float* __restrict__ dinv,
                                                 int n, int per) {
  __shared__ int ws[4];
  int b = blockIdx.x;
  int start = b * per, end = min(n, start + per);
  int s = 0;
  for (int i = start + threadIdx.x; i < end; i += 256) {
    int c = counts[i];
    s += c;
    dinv[i] = rsqrtf((float)c + 1.0f);  // deg = indeg + 1 (self loop)
  }
#pragma unroll
  for (int d = 1; d < 64; d <<= 1) s += __shfl_xor(s, d);
  if ((threadIdx.x & 63) == 0) ws[threadIdx.x >> 6] = s;
  __syncthreads();
  if (threadIdx.x == 0) blockSums[b] = ws[0] + ws[1] + ws[2] + ws[3];
}

// phase B: block b derives its base offset from blockSums, scans its chunk
__global__ __launch_bounds__(256) void scan_final(const int* __restrict__ counts,
                                                  const int* __restrict__ blockSums,
                                                  int* __restrict__ row_ptr,
                                                  int n, int per) {
  __shared__ int wsum[4];
  __shared__ int sbase;
  int tid = threadIdx.x, lane = tid & 63, wid = tid >> 6;
  int b = blockIdx.x;
  {
    int v = (tid < b) ? blockSums[tid] : 0;
#pragma unroll
    for (int d = 1; d < 64; d <<= 1) v += __shfl_xor(v, d);
    if (lane == 0) wsum[wid] = v;
    __syncthreads();
    if (tid == 0) sbase = wsum[0] + wsum[1] + wsum[2] + wsum[3];
    __syncthreads();
  }
  int start = b * per, end = min(n + 1, start + per);
  for (int chunk = start; chunk < end; chunk += 256) {
    int idx = chunk + tid;
    int v = (idx < n) ? counts[idx] : 0;
    int x = v;
#pragma unroll
    for (int d = 1; d < 64; d <<= 1) {
      int y = __shfl_up(x, d, 64);
      if (lane >= d) x += y;
    }
    if (lane == 63) wsum[wid] = x;
    __syncthreads();
    if (tid == 0) {
      int run = sbase;
#pragma unroll
      for (int w = 0; w < 4; ++w) { int t = wsum[w]; wsum[w] = run; run += t; }
      sbase = run;
    }
    __syncthreads();
    if (idx < end) row_ptr[idx] = wsum[wid] + x - v;
    __syncthreads();
  }
}

// edges[row_ptr[d]+ofs[e]] = {src, dinv[src]*dinv[dst]}  (no atomics)
__global__ __launch_bounds__(256) void place_kernel(const int* __restrict__ src,
                                                    const int* __restrict__ dst,
                                                    const int* __restrict__ row_ptr,
                                                    const int* __restrict__ ofs,
                                                    const float* __restrict__ dinv,
                                                    int2* __restrict__ edges, int E) {
  int e = blockIdx.x * 256 + threadIdx.x;
  if (e < E) {
    int d = dst[e], s = src[e];
    int pos = row_ptr[d] + ofs[e];
    int2 ed; ed.x = s; ed.y = __float_as_int(dinv[s] * dinv[d]);
    edges[pos] = ed;
  }
}

// ---------------- Conversions (x + all weights, one launch) ----------------

__global__ __launch_bounds__(256) void cvt_all(const float* __restrict__ x,
                                               short* __restrict__ x_bf, int n4,
                                               const float* __restrict__ W1,
                                               short* __restrict__ w1t,
                                               const float* __restrict__ W2,
                                               short* __restrict__ w2t,
                                               const float* __restrict__ W3,
                                               short* __restrict__ w3t) {
  int i = blockIdx.x * 256 + threadIdx.x;
  if (i < n4) {
    float4 v = ((const float4*)x)[i];
    short4 o;
    o.x = f2bf(v.x); o.y = f2bf(v.y); o.z = f2bf(v.z); o.w = f2bf(v.w);
    ((short4*)x_bf)[i] = o;
    return;
  }
  int j = i - n4;
  if (j < 32768) {                       // W1 [k=128][n=256]
    int k = j >> 8, n = j & 255;
    w1t[n * 128 + k] = f2bf(W1[j]);
  } else if (j < 65536) {                // W2 [k=256][n=128]
    int jj = j - 32768; int k = jj >> 7, n = jj & 127;
    w2t[n * 256 + k] = f2bf(W2[jj]);
  } else if (j < 81920) {                // W3 [k=128][n=128]
    int jj = j - 65536; int k = jj >> 7, n = jj & 127;
    w3t[n * 128 + k] = f2bf(W3[jj]);
  }
}

// ---------------- bf16 MFMA GEMM: C[M,N] = A[M,K] @ BT[N,K]^T (+bias) -------
// 128x128 tile, BK=128, XOR-swizzled LDS, LDS-staged coalesced bf16 C stores.
// MODE 1: plain; MODE 2: + non-atomic BN partials; MODE 3: BN-apply+ReLU
// fused into A staging.

template <int MODE>
__global__ __launch_bounds__(256, 2) void bgemm_big(const short* __restrict__ A,
                                                    const short* __restrict__ BT,
                                                    const float* __restrict__ bias,
                                                    short* __restrict__ Cout,
                                                    float* __restrict__ pS,
                                                    float* __restrict__ pSS,
                                                    const float* __restrict__ bnp,
                                                    int M, int N, int K) {
  __shared__ short smem[2 * 128 * 128];  // 64 KB
  short* As = smem;
  short* Bs = smem + 128 * 128;
  const int tid = threadIdx.x;
  const int w = tid >> 6, lane = tid & 63;
  const int wM = w >> 1, wN = w & 1;
  const int rowBase = blockIdx.y * 128;
  const int colBase = blockIdx.x * 128;
  const int l15 = lane & 15, q = lane >> 4;

  f32x4 acc[4][4];
#pragma unroll
  for (int i = 0; i < 4; ++i)
#pragma unroll
    for (int j = 0; j < 4; ++j) acc[i][j] = (f32x4){0.f, 0.f, 0.f, 0.f};

  for (int k0 = 0; k0 < K; k0 += 128) {
    if (MODE == 3) {
#pragma unroll
      for (int it = 0; it < 8; ++it) {
        int p = it * 256 + tid;
        int row = p >> 4, kcp = p & 15;
        int kc = kcp ^ (row & 15);
        int gm = rowBase + row; if (gm >= M) gm = M - 1;
        int c = k0 + kc * 8;
        bf16x8 av = *(const bf16x8*)&A[(size_t)gm * K + c];
        float4 s0 = *(const float4*)&bnp[c];
        float4 s1 = *(const float4*)&bnp[c + 4];
        float4 h0 = *(const float4*)&bnp[K + c];
        float4 h1 = *(const float4*)&bnp[K + c + 4];
        short res[8];
        res[0] = f2bf(fmaxf(bfs(av[0]) * s0.x + h0.x, 0.f));
        res[1] = f2bf(fmaxf(bfs(av[1]) * s0.y + h0.y, 0.f));
        res[2] = f2bf(fmaxf(bfs(av[2]) * s0.z + h0.z, 0.f));
        res[3] = f2bf(fmaxf(bfs(av[3]) * s0.w + h0.w, 0.f));
        res[4] = f2bf(fmaxf(bfs(av[4]) * s1.x + h1.x, 0.f));
        res[5] = f2bf(fmaxf(bfs(av[5]) * s1.y + h1.y, 0.f));
        res[6] = f2bf(fmaxf(bfs(av[6]) * s1.z + h1.z, 0.f));
        res[7] = f2bf(fmaxf(bfs(av[7]) * s1.w + h1.w, 0.f));
        bf16x8 rv;
#pragma unroll
        for (int j = 0; j < 8; ++j) rv[j] = res[j];
        *(bf16x8*)&As[p * 8] = rv;
      }
    } else {
#pragma unroll
      for (int it = 0; it < 8; ++it) {
        int p = it * 256 + tid;
        int row = p >> 4, kcp = p & 15;
        int kc = kcp ^ (row & 15);
        int gm = rowBase + row; if (gm >= M) gm = M - 1;  // clamp; stores guarded
        async_cp16(A + (size_t)gm * K + k0 + kc * 8, &As[(it * 256 + w * 64) * 8]);
      }
    }
#pragma unroll
    for (int it = 0; it < 8; ++it) {
      int p = it * 256 + tid;
      int row = p >> 4, kcp = p & 15;
      int kc = kcp ^ (row & 15);
      async_cp16(BT + (size_t)(colBase + row) * K + k0 + kc * 8,
                 &Bs[(it * 256 + w * 64) * 8]);
    }
    __syncthreads();

#pragma unroll
    for (int ks = 0; ks < 4; ++ks) {
      bf16x8 af[4], bfr[4];
#pragma unroll
      for (int tm = 0; tm < 4; ++tm) {
        int row = wM * 64 + tm * 16 + l15;
        int kcp = (ks * 4 + q) ^ l15;
        af[tm] = *(const bf16x8*)&As[(row * 16 + kcp) * 8];
      }
#pragma unroll
      for (int tn = 0; tn < 4; ++tn) {
        int row = wN * 64 + tn * 16 + l15;
        int kcp = (ks * 4 + q) ^ l15;
        bfr[tn] = *(const bf16x8*)&Bs[(row * 16 + kcp) * 8];
      }
#pragma unroll
      for (int tm = 0; tm < 4; ++tm)
#pragma unroll
        for (int tn = 0; tn < 4; ++tn)
          acc[tm][tn] = __builtin_amdgcn_mfma_f32_16x16x32_bf16(af[tm], bfr[tn],
                                                                acc[tm][tn], 0, 0, 0);
    }
    __syncthreads();
  }

  if (MODE == 2) {
#pragma unroll
    for (int tn = 0; tn < 4; ++tn) {
      int col = colBase + wN * 64 + tn * 16 + l15;
      float bv = bias ? bias[col] : 0.0f;
      float s = 0.f, ss = 0.f;
#pragma unroll
      for (int tm = 0; tm < 4; ++tm) {
        int r0 = rowBase + wM * 64 + tm * 16 + q * 4;
#pragma unroll
        for (int r = 0; r < 4; ++r) {
          if (r0 + r < M) { float v = acc[tm][tn][r] + bv; s += v; ss += v * v; }
        }
      }
      s += __shfl_xor(s, 16); s += __shfl_xor(s, 32);
      ss += __shfl_xor(ss, 16); ss += __shfl_xor(ss, 32);
      if (q == 0) {
        int prow = blockIdx.y * 2 + wM;
        pS[(size_t)prow * C_HID + col] = s;
        pSS[(size_t)prow * C_HID + col] = ss;
      }
    }
  }

  {
    short* S = As;
#pragma unroll
    for (int tn = 0; tn < 4; ++tn) {
      int col = wN * 64 + tn * 16 + l15;
      float bv = bias ? bias[colBase + col] : 0.0f;
#pragma unroll
      for (int tm = 0; tm < 4; ++tm) {
        int r0 = wM * 64 + tm * 16 + q * 4;
#pragma unroll
        for (int r = 0; r < 4; ++r) S[(r0 + r) * 128 + col] = f2bf(acc[tm][tn][r] + bv);
      }
    }
    __syncthreads();
#pragma unroll
    for (int it = 0; it < 8; ++it) {
      int p = it * 256 + tid;
      int row = p >> 4, c = p & 15;
      int gm = rowBase + row;
      if (gm < M)
        *(uint4*)&Cout[(size_t)gm * N + colBase + c * 8] = ((const uint4*)S)[p];
    }
  }
}

// ---------------- BN stats tree reduce ----------------

__global__ __launch_bounds__(256) void bn_red1_kernel(const float* __restrict__ pS,
                                                      const float* __restrict__ pSS,
                                                      float* __restrict__ oS,
                                                      float* __restrict__ oSS, int R) {
  int c = threadIdx.x;
  int per = (R + gridDim.x - 1) / gridDim.x;
  int r0 = blockIdx.x * per, r1 = min(R, r0 + per);
  float s = 0.f, ss = 0.f;
  for (int r = r0; r < r1; ++r) {
    s += pS[(size_t)r * C_HID + c];
    ss += pSS[(size_t)r * C_HID + c];
  }
  oS[(size_t)blockIdx.x * C_HID + c] = s;
  oSS[(size_t)blockIdx.x * C_HID + c] = ss;
}

__global__ __launch_bounds__(256) void bn_red2_kernel(const float* __restrict__ oS,
                                                      const float* __restrict__ oSS,
                                                      const float* __restrict__ gamma,
                                                      const float* __restrict__ beta,
                                                      float* __restrict__ bnp,
                                                      int G, float invN) {
  int c = threadIdx.x;
  float s = 0.f, ss = 0.f;
  for (int g = 0; g < G; ++g) {
    s += oS[(size_t)g * C_HID + c];
    ss += oSS[(size_t)g * C_HID + c];
  }
  float mu = s * invN;
  float var = ss * invN - mu * mu;
  float sc = gamma[c] * rsqrtf(var + 1e-5f);
  bnp[c] = sc;
  bnp[C_HID + c] = beta[c] - mu * sc;
}

// ---------------- Aggregations: 16-lane group per node, unroll x4 ----------

__global__ __launch_bounds__(256) void agg_x_kernel(const uint4* __restrict__ xb4,
                                                    const float* __restrict__ dinv,
                                                    const int* __restrict__ row_ptr,
                                                    const int2* __restrict__ edges,
                                                    uint4* __restrict__ out4, int N) {
  int g = (blockIdx.x * 256 + threadIdx.x) >> 4;
  int sl = threadIdx.x & 15;
  if (g >= N) return;
  int e0 = row_ptr[g], e1 = row_ptr[g + 1];
  float a[8] = {0.f, 0.f, 0.f, 0.f, 0.f, 0.f, 0.f, 0.f};
  int e = e0;
  for (; e + 4 <= e1; e += 4) {
    int2 ed0 = edges[e], ed1 = edges[e + 1], ed2 = edges[e + 2], ed3 = edges[e + 3];
    uint4 p0 = xb4[(size_t)ed0.x * 16 + sl];
    uint4 p1 = xb4[(size_t)ed1.x * 16 + sl];
    uint4 p2 = xb4[(size_t)ed2.x * 16 + sl];
    uint4 p3 = xb4[(size_t)ed3.x * 16 + sl];
    acc8(a, p0, __int_as_float(ed0.y));
    acc8(a, p1, __int_as_float(ed1.y));
    acc8(a, p2, __int_as_float(ed2.y));
    acc8(a, p3, __int_as_float(ed3.y));
  }
  for (; e < e1; ++e) {
    int2 ed = edges[e];
    uint4 p = xb4[(size_t)ed.x * 16 + sl];
    acc8(a, p, __int_as_float(ed.y));
  }
  float dn = dinv[g];
  uint4 ps = xb4[(size_t)g * 16 + sl];
  acc8(a, ps, dn * dn);
  uint4 o;
  o.x = pack_bf2(a[0], a[1]); o.y = pack_bf2(a[2], a[3]);
  o.z = pack_bf2(a[4], a[5]); o.w = pack_bf2(a[6], a[7]);
  out4[(size_t)g * 16 + sl] = o;
}

__global__ __launch_bounds__(256) void agg_ln_kernel(const uint4* __restrict__ hb4,
                                                     const float* __restrict__ dinv,
                                                     const int* __restrict__ row_ptr,
                                                     const int2* __restrict__ edges,
                                                     const float* __restrict__ bias,
                                                     const float* __restrict__ gamma,
                                                     const float* __restrict__ beta,
                                                     uint4* __restrict__ zb4, int N) {
  int g = (blockIdx.x * 256 + threadIdx.x) >> 4;
  int sl = threadIdx.x & 15;
  if (g >= N) return;
  int e0 = row_ptr[g], e1 = row_ptr[g + 1];
  float a[8] = {0.f, 0.f, 0.f, 0.f, 0.f, 0.f, 0.f, 0.f};
  int e = e0;
  for (; e + 4 <= e1; e += 4) {
    int2 ed0 = edges[e], ed1 = edges[e + 1], ed2 = edges[e + 2], ed3 = edges[e + 3];
    uint4 p0 = hb4[(size_t)ed0.x * 16 + sl];
    uint4 p1 = hb4[(size_t)ed1.x * 16 + sl];
    uint4 p2 = hb4[(size_t)ed2.x * 16 + sl];
    uint4 p3 = hb4[(size_t)ed3.x * 16 + sl];
    acc8(a, p0, __int_as_float(ed0.y));
    acc8(a, p1, __int_as_float(ed1.y));
    acc8(a, p2, __int_as_float(ed2.y));
    acc8(a, p3, __int_as_float(ed3.y));
  }
  for (; e < e1; ++e) {
    int2 ed = edges[e];
    uint4 p = hb4[(size_t)ed.x * 16 + sl];
    acc8(a, p, __int_as_float(ed.y));
  }
  float dn = dinv[g];
  uint4 ps = hb4[(size_t)g * 16 + sl];
  acc8(a, ps, dn * dn);

  int c = sl * 8;
  float4 bv0 = *(const float4*)&bias[c];
  float4 bv1 = *(const float4*)&bias[c + 4];
  a[0] += bv0.x; a[1] += bv0.y; a[2] += bv0.z; a[3] += bv0.w;
  a[4] += bv1.x; a[5] += bv1.y; a[6] += bv1.z; a[7] += bv1.w;

  float s = 0.f, ss = 0.f;
#pragma unroll
  for (int j = 0; j < 8; ++j) { s += a[j]; ss += a[j] * a[j]; }
#pragma unroll
  for (int d = 1; d < 16; d <<= 1) {
    s += __shfl_xor(s, d);
    ss += __shfl_xor(ss, d);
  }
  float mu = s * (1.0f / C_OUT);
  float var = ss * (1.0f / C_OUT) - mu * mu;
  float rs = rsqrtf(var + 1e-5f);
  float4 g0 = *(const float4*)&gamma[c];
  float4 g1 = *(const float4*)&gamma[c + 4];
  float4 t0 = *(const float4*)&beta[c];
  float4 t1 = *(const float4*)&beta[c + 4];
  float o[8];
  o[0] = fmaxf((a[0] - mu) * rs * g0.x + t0.x, 0.0f);
  o[1] = fmaxf((a[1] - mu) * rs * g0.y + t0.y, 0.0f);
  o[2] = fmaxf((a[2] - mu) * rs * g0.z + t0.z, 0.0f);
  o[3] = fmaxf((a[3] - mu) * rs * g0.w + t0.w, 0.0f);
  o[4] = fmaxf((a[4] - mu) * rs * g1.x + t1.x, 0.0f);
  o[5] = fmaxf((a[5] - mu) * rs * g1.y + t1.y, 0.0f);
  o[6] = fmaxf((a[6] - mu) * rs * g1.z + t1.z, 0.0f);
  o[7] = fmaxf((a[7] - mu) * rs * g1.w + t1.w, 0.0f);
  uint4 ov;
  ov.x = pack_bf2(o[0], o[1]); ov.y = pack_bf2(o[2], o[3]);
  ov.z = pack_bf2(o[4], o[5]); ov.w = pack_bf2(o[6], o[7]);
  zb4[(size_t)g * 16 + sl] = ov;
}

// ---------------- Decode: 16-lane group per pair, bf16 z rows ---------------

__global__ __launch_bounds__(256) void decode_kernel(const uint4* __restrict__ zb4,
                                                     const int* __restrict__ eli,
                                                     const float* __restrict__ cutoff,
                                                     float* __restrict__ out, int EL) {
  int g = (blockIdx.x * 256 + threadIdx.x) >> 4;
  int sl = threadIdx.x & 15;
  if (g >= EL) return;
  int a = eli[g];
  int b = eli[EL + g];
  uint4 va = zb4[(size_t)a * 16 + sl];
  uint4 vb = zb4[(size_t)b * 16 + sl];
  float s = bflo(va.x) * bflo(vb.x) + bfhi(va.x) * bfhi(vb.x)
          + bflo(va.y) * bflo(vb.y) + bfhi(va.y) * bfhi(vb.y)
          + bflo(va.z) * bflo(vb.z) + bfhi(va.z) * bfhi(vb.z)
          + bflo(va.w) * bflo(vb.w) + bfhi(va.w) * bfhi(vb.w);
#pragma unroll
  for (int d = 1; d < 16; d <<= 1) s += __shfl_xor(s, d);
  if (sl == 0) {
    out[g] = s;
    out[EL + g] = (s < cutoff[0]) ? 0.0f : 1.0f;
  }
}

// ---------------- Launch ----------------

extern "C" void kernel_launch(void* const* d_in, const int* in_sizes, int n_in,
                              void* d_out, int out_size, void* d_ws, size_t ws_size,
                              hipStream_t stream) {
  const float* x        = (const float*)d_in[0];
  const int*   eidx     = (const int*)d_in[1];
  const int*   eli      = (const int*)d_in[2];
  const float* cutoff   = (const float*)d_in[3];
  const float* W1       = (const float*)d_in[4];
  const float* b1       = (const float*)d_in[5];
  const float* bn_gamma = (const float*)d_in[6];
  const float* bn_beta  = (const float*)d_in[7];
  const float* W2       = (const float*)d_in[8];
  const float* b2       = (const float*)d_in[9];
  const float* ln_gamma = (const float*)d_in[10];
  const float* ln_beta  = (const float*)d_in[11];
  const float* lin_W    = (const float*)d_in[12];
  const float* lin_b    = (const float*)d_in[13];
  float* out = (float*)d_out;

  const int N  = in_sizes[0] / C_IN;   // 100000
  const int E  = in_sizes[1] / 2;      // 800000
  const int EL = in_sizes[2] / 2;      // 200000

  const int* src = eidx;
  const int* dst = eidx + E;

  const int MB = (N + 127) / 128;
  const int R  = 2 * MB;

  // workspace layout
  char* p = (char*)d_ws;
  short* regionA = (short*)p;  p += (size_t)N * 256 * 2;  // x_bf+xa_bf, later zf_bf
  short* regionB = (short*)p;  p += (size_t)N * 256 * 2;  // h1_bf, later z_bf
  short* h2_bf   = (short*)p;  p += (size_t)N * 128 * 2;
  float* dinv    = (float*)p;  p += (size_t)N * 4;
  int* counts    = (int*)p;    p += (size_t)N * 4;
  int* row_ptr   = (int*)p;    p += (size_t)(N + 4) * 4;
  int* ofs       = (int*)p;    p += (size_t)E * 4;
  int2* edges    = (int2*)p;   p += (size_t)E * 8;
  float* pS      = (float*)p;  p += (size_t)R * C_HID * 4;
  float* pSS     = (float*)p;  p += (size_t)R * C_HID * 4;
  float* oS      = (float*)p;  p += 32 * C_HID * 4;
  float* oSS     = (float*)p;  p += 32 * C_HID * 4;
  float* bnp     = (float*)p;  p += 2 * C_HID * 4;
  int* blockSums = (int*)p;    p += SCAN_B * 4;
  short* w1t     = (short*)p;  p += (size_t)C_HID * C_IN * 2;
  short* w2t     = (short*)p;  p += (size_t)C_OUT * C_HID * 2;
  short* w3t     = (short*)p;  p += (size_t)C_OUT * C_OUT * 2;

  short* x_bf   = regionA;                    // [N][128]
  short* xa_bf  = regionA + (size_t)N * 128;  // [N][128]
  short* h1_bf  = regionB;                    // [N][256]
  short* z_bf   = regionB;                    // [N][128] (h1 dead after GEMM2)
  short* zf_bf  = regionA;                    // [N][128] (x/xa dead after GEMM1)

  hipMemsetAsync(counts, 0, (size_t)N * 4, stream);

  int eb = (E + 255) / 256;

  hist_kernel<<<eb, 256, 0, stream>>>(dst, counts, ofs, E);

  int per = (N + 1 + SCAN_B - 1) / SCAN_B;
  scan_part<<<SCAN_B, 256, 0, stream>>>(counts, blockSums, dinv, N, per);
  scan_final<<<SCAN_B, 256, 0, stream>>>(counts, blockSums, row_ptr, N, per);

  place_kernel<<<eb, 256, 0, stream>>>(src, dst, row_ptr, ofs, dinv, edges, E);

  int xn4 = N * C_IN / 4;
  cvt_all<<<(xn4 + 81920 + 255) / 256, 256, 0, stream>>>(x, x_bf, xn4, W1, w1t,
                                                         W2, w2t, lin_W, w3t);

  int gb = ((size_t)N * 16 + 255) / 256;  // 16-lane group per node
  agg_x_kernel<<<gb, 256, 0, stream>>>((const uint4*)x_bf, dinv, row_ptr, edges,
                                       (uint4*)xa_bf, N);

  // GEMM1: h1 = agg(x) @ W1 + b1  [N x 256] bf16 + BN partials
  dim3 g1(C_HID / 128, MB);
  bgemm_big<2><<<g1, 256, 0, stream>>>(xa_bf, w1t, b1, h1_bf, pS, pSS, nullptr,
                                       N, C_HID, C_IN);

  bn_red1_kernel<<<32, 256, 0, stream>>>(pS, pSS, oS, oSS, R);
  bn_red2_kernel<<<1, 256, 0, stream>>>(oS, oSS, bn_gamma, bn_beta, bnp, 32,
                                        1.0f / (float)N);

  // GEMM2: h2raw = relu(bn(h1)) @ W2  [N x 128] bf16; BN fused into A staging
  dim3 g2(C_OUT / 128, MB);
  bgemm_big<3><<<g2, 256, 0, stream>>>(h1_bf, w2t, nullptr, h2_bf, nullptr, nullptr,
                                       bnp, N, C_OUT, C_HID);

  agg_ln_kernel<<<gb, 256, 0, stream>>>((const uint4*)h2_bf, dinv, row_ptr, edges,
                                        b2, ln_gamma, ln_beta, (uint4*)z_bf, N);

  // GEMM3: zf = z @ lin_W + lin_b  [N x 128] bf16
  dim3 g3(C_OUT / 128, MB);
  bgemm_big<1><<<g3, 256, 0, stream>>>(z_bf, w3t, lin_b, zf_bf, nullptr, nullptr,
                                       nullptr, N, C_OUT, C_OUT);

  int db = ((size_t)EL * 16 + 255) / 256;  // 16-lane group per pair
  decode_kernel<<<db, 256, 0, stream>>>((const uint4*)zf_bf, eli, cutoff, out, EL);
}